// Round 1
// baseline (740.729 us; speedup 1.0000x reference)
//
#include <hip/hip_runtime.h>
#include <stdint.h>
#include <stddef.h>

typedef __bf16 bf16;
typedef __attribute__((ext_vector_type(8))) __bf16 bf16x8;
typedef __attribute__((ext_vector_type(4))) __bf16 bf16x4;
typedef __attribute__((ext_vector_type(4))) float f32x4;

#define ATT_EPS 1e-6f

// async global->LDS, 16B per lane; LDS dest = wave-uniform base + lane*16
__device__ __forceinline__ void lds16(const void* g, void* l) {
    __builtin_amdgcn_global_load_lds(
        (const __attribute__((address_space(1))) void*)g,
        (__attribute__((address_space(3))) void*)l, 16, 0, 0);
}

// ---------------------------------------------------------------------------
// fp32 -> bf16 bulk convert (x)
// ---------------------------------------------------------------------------
__global__ __launch_bounds__(256) void cvt_bf16(const float4* __restrict__ in,
                                                bf16x4* __restrict__ out, int n4) {
    int i = blockIdx.x * 256 + threadIdx.x;
    if (i < n4) {
        float4 v = in[i];
        bf16x4 o;
        o.x = (bf16)v.x; o.y = (bf16)v.y; o.z = (bf16)v.z; o.w = (bf16)v.w;
        out[i] = o;
    }
}

// ---------------------------------------------------------------------------
// W (K x N fp32, row-major) -> Wt (N x K bf16, row-major)
// ---------------------------------------------------------------------------
__global__ __launch_bounds__(256) void transpose_w(const float* __restrict__ W,
                                                   bf16* __restrict__ Wt) {
    __shared__ float tile[32][33];
    const int bx = blockIdx.x * 32, by = blockIdx.y * 32;
    const int tx = threadIdx.x, ty = threadIdx.y; // 32 x 8
#pragma unroll
    for (int j = 0; j < 32; j += 8)
        tile[ty + j][tx] = W[(size_t)(by + ty + j) * 1024 + bx + tx];
    __syncthreads();
#pragma unroll
    for (int j = 0; j < 32; j += 8)
        Wt[(size_t)(bx + ty + j) * 1024 + by + tx] = (bf16)tile[tx][ty + j];
}

// ---------------------------------------------------------------------------
// C[m][n] = sum_k A[m][k] * Bt[n][k]   (both operands k-contiguous, bf16)
// 128x128 tile, BK=32, 4 waves of 64x64, mfma_f32_16x16x32_bf16 (m97 recipe)
// MODE: 0 = store fp32, 1 = store bf16, 2 = phi(x)=elu(x)+1 then bf16
// ---------------------------------------------------------------------------
template <int MODE>
__global__ __launch_bounds__(256) void gemm_bt(const bf16* __restrict__ A, int lda,
                                               const bf16* __restrict__ B, int ldb,
                                               void* __restrict__ C, int ldc, int K) {
    __shared__ bf16 sA[128 * 32] __attribute__((aligned(16)));
    __shared__ bf16 sB[128 * 32] __attribute__((aligned(16)));
    const int t = threadIdx.x;
    const int wave = t >> 6;
    const int lane = t & 63;
    const int tileM = blockIdx.y * 128;
    const int tileN = blockIdx.x * 128;
    const int wm = (wave >> 1) * 64;
    const int wn = (wave & 1) * 64;

    f32x4 acc[4][4] = {};

    const int srow = t >> 2;          // 0..63
    const int scol = (t & 3) * 8;     // k offset within BK
    const bf16* a0 = A + (size_t)(tileM + srow) * lda + scol;
    const bf16* a1 = A + (size_t)(tileM + 64 + srow) * lda + scol;
    const bf16* b0 = B + (size_t)(tileN + srow) * ldb + scol;
    const bf16* b1 = B + (size_t)(tileN + 64 + srow) * ldb + scol;
    bf16* dA0 = sA + wave * 512;
    bf16* dA1 = sA + 2048 + wave * 512;
    bf16* dB0 = sB + wave * 512;
    bf16* dB1 = sB + 2048 + wave * 512;

    const int rm = lane & 15;
    const int qk = (lane >> 4) * 8;

    for (int k0 = 0; k0 < K; k0 += 32) {
        lds16(a0 + k0, dA0);
        lds16(a1 + k0, dA1);
        lds16(b0 + k0, dB0);
        lds16(b1 + k0, dB1);
        __builtin_amdgcn_s_waitcnt(0);
        __syncthreads();
        bf16x8 af[4], bfr[4];
#pragma unroll
        for (int mi = 0; mi < 4; mi++)
            af[mi] = *(const bf16x8*)&sA[(wm + mi * 16 + rm) * 32 + qk];
#pragma unroll
        for (int ni = 0; ni < 4; ni++)
            bfr[ni] = *(const bf16x8*)&sB[(wn + ni * 16 + rm) * 32 + qk];
#pragma unroll
        for (int mi = 0; mi < 4; mi++)
#pragma unroll
            for (int ni = 0; ni < 4; ni++)
                acc[mi][ni] = __builtin_amdgcn_mfma_f32_16x16x32_bf16(
                    af[mi], bfr[ni], acc[mi][ni], 0, 0, 0);
        __syncthreads();
    }

    const int row0 = (lane >> 4) * 4;
    const int col = lane & 15;
#pragma unroll
    for (int mi = 0; mi < 4; mi++) {
#pragma unroll
        for (int ni = 0; ni < 4; ni++) {
#pragma unroll
            for (int r = 0; r < 4; r++) {
                int gm = tileM + wm + mi * 16 + row0 + r;
                int gn = tileN + wn + ni * 16 + col;
                float v = acc[mi][ni][r];
                if (MODE == 2) v = (v > 0.f) ? (v + 1.f) : __expf(v);
                if (MODE == 0)
                    ((float*)C)[(size_t)gm * ldc + gn] = v;
                else
                    ((bf16*)C)[(size_t)gm * ldc + gn] = (bf16)v;
            }
        }
    }
}

// ---------------------------------------------------------------------------
// Phase 2: per (b,h):  KvT[n][m] += sum_l Kf[l][m] V[l][n];  KvT[64][m] = K1[m]
// A = Kft rows (h*64..+63), Bt = Vt rows (h*64..+63), K = l chunk of 2048.
// ones-fragment MFMA accumulates K1 for free.
// ---------------------------------------------------------------------------
__global__ __launch_bounds__(256) void kv_reduce(const bf16* __restrict__ Kft,
                                                 const bf16* __restrict__ Vt,
                                                 float* __restrict__ Kv) {
    const int chunk = blockIdx.x; // 0..3
    const int bh = blockIdx.y;    // 0..63
    const int b = bh >> 4, h = bh & 15;
    __shared__ bf16 sA[64 * 32] __attribute__((aligned(16)));
    __shared__ bf16 sB[64 * 32] __attribute__((aligned(16)));
    const int t = threadIdx.x, wave = t >> 6, lane = t & 63;
    const size_t cbase = (size_t)b * 8192 + (size_t)chunk * 2048;
    const int srow = t >> 2, scol = (t & 3) * 8;
    const bf16* a0 = Kft + (size_t)(h * 64 + srow) * 32768 + cbase + scol;
    const bf16* b0 = Vt + (size_t)(h * 64 + srow) * 32768 + cbase + scol;
    bf16* dA = sA + wave * 512;
    bf16* dB = sB + wave * 512;
    const int rm = lane & 15, qk = (lane >> 4) * 8;

    f32x4 acc[4] = {};
    f32x4 acc1 = {0.f, 0.f, 0.f, 0.f};
    bf16x8 ones;
#pragma unroll
    for (int j = 0; j < 8; j++) ones[j] = (bf16)1.0f;

    for (int k0 = 0; k0 < 2048; k0 += 32) {
        lds16(a0 + k0, dA);
        lds16(b0 + k0, dB);
        __builtin_amdgcn_s_waitcnt(0);
        __syncthreads();
        bf16x8 af = *(const bf16x8*)&sA[(wave * 16 + rm) * 32 + qk];
        bf16x8 bfr[4];
#pragma unroll
        for (int ni = 0; ni < 4; ni++)
            bfr[ni] = *(const bf16x8*)&sB[(ni * 16 + rm) * 32 + qk];
#pragma unroll
        for (int ni = 0; ni < 4; ni++)
            acc[ni] = __builtin_amdgcn_mfma_f32_16x16x32_bf16(af, bfr[ni], acc[ni], 0, 0, 0);
        acc1 = __builtin_amdgcn_mfma_f32_16x16x32_bf16(af, ones, acc1, 0, 0, 0);
        __syncthreads();
    }

    float* out = Kv + bh * 65 * 64;
    const int row0 = (lane >> 4) * 4, col = lane & 15;
    const int m0 = wave * 16 + row0;
#pragma unroll
    for (int ni = 0; ni < 4; ni++)
#pragma unroll
        for (int r = 0; r < 4; r++)
            atomicAdd(&out[(ni * 16 + col) * 64 + m0 + r], acc[ni][r]);
    if (col == 0) {
#pragma unroll
        for (int r = 0; r < 4; r++) atomicAdd(&out[64 * 64 + m0 + r], acc1[r]);
    }
}

// ---------------------------------------------------------------------------
// Phase 3: attn[l][h*64+n] = (sum_m Qf[l][m] KvT[n][m]) / (dot(Qf, K1) + eps)
// One block = 128 l-rows of one (b,h). K = 64, N = 65 (col 64 = den).
// ---------------------------------------------------------------------------
__global__ __launch_bounds__(256) void attn_out(const bf16* __restrict__ Qf,
                                                const float* __restrict__ Kv,
                                                bf16* __restrict__ attn) {
    const int lt = blockIdx.x; // 0..63
    const int bh = blockIdx.y; // 0..63
    const int b = bh >> 4, h = bh & 15;
    __shared__ bf16 sQ[128 * 64] __attribute__((aligned(16)));
    __shared__ bf16 sB[80 * 64] __attribute__((aligned(16)));
    __shared__ float den[128];
    const int t = threadIdx.x, wave = t >> 6, lane = t & 63;
    const int qrow = t >> 3, qc = (t & 7) * 8;
    const bf16* qp = Qf + (size_t)(b * 8192 + lt * 128 + qrow) * 1024 + h * 64 + qc;
#pragma unroll
    for (int i = 0; i < 4; i++)
        lds16(qp + (size_t)i * 32 * 1024, sQ + i * 2048 + wave * 512);
    const float* kv = Kv + bh * 65 * 64;
    for (int idx = t; idx < 80 * 64; idx += 256) {
        int n = idx >> 6, k2 = idx & 63;
        sB[idx] = (n < 65) ? (bf16)kv[n * 64 + k2] : (bf16)0.f;
    }
    __builtin_amdgcn_s_waitcnt(0);
    __syncthreads();

    f32x4 acc[2][5] = {};
    const int rm = lane & 15, qk = (lane >> 4) * 8;
#pragma unroll
    for (int k0 = 0; k0 < 64; k0 += 32) {
        bf16x8 af[2], bfr[5];
#pragma unroll
        for (int mi = 0; mi < 2; mi++)
            af[mi] = *(const bf16x8*)&sQ[(wave * 32 + mi * 16 + rm) * 64 + k0 + qk];
#pragma unroll
        for (int ni = 0; ni < 5; ni++)
            bfr[ni] = *(const bf16x8*)&sB[(ni * 16 + rm) * 64 + k0 + qk];
#pragma unroll
        for (int mi = 0; mi < 2; mi++)
#pragma unroll
            for (int ni = 0; ni < 5; ni++)
                acc[mi][ni] = __builtin_amdgcn_mfma_f32_16x16x32_bf16(
                    af[mi], bfr[ni], acc[mi][ni], 0, 0, 0);
    }

    const int row0 = (lane >> 4) * 4, col = lane & 15;
    if (col == 0) {
#pragma unroll
        for (int mi = 0; mi < 2; mi++)
#pragma unroll
            for (int r = 0; r < 4; r++)
                den[wave * 32 + mi * 16 + row0 + r] = acc[mi][4][r] + ATT_EPS;
    }
    __syncthreads();
#pragma unroll
    for (int mi = 0; mi < 2; mi++) {
#pragma unroll
        for (int ni = 0; ni < 4; ni++) {
#pragma unroll
            for (int r = 0; r < 4; r++) {
                int rl = wave * 32 + mi * 16 + row0 + r;
                float v = acc[mi][ni][r] / den[rl];
                attn[(size_t)(b * 8192 + lt * 128 + rl) * 1024 + h * 64 + ni * 16 + col] =
                    (bf16)v;
            }
        }
    }
}

// ---------------------------------------------------------------------------
extern "C" void kernel_launch(void* const* d_in, const int* in_sizes, int n_in,
                              void* d_out, int out_size, void* d_ws, size_t ws_size,
                              hipStream_t stream) {
    const float* x  = (const float*)d_in[0];
    const float* Wq = (const float*)d_in[1];
    const float* Wk = (const float*)d_in[2];
    const float* Wv = (const float*)d_in[3];
    const float* Wo = (const float*)d_in[4];

    char* ws = (char*)d_ws;
    bf16* xb  = (bf16*)ws;                           // 64 MB, reused as attn
    bf16* Qf  = (bf16*)(ws + ((size_t)64 << 20));    // 64 MB
    bf16* Kft = (bf16*)(ws + ((size_t)128 << 20));   // 64 MB
    bf16* Vt  = (bf16*)(ws + ((size_t)192 << 20));   // 64 MB
    bf16* Wqt = (bf16*)(ws + ((size_t)256 << 20));   // 2 MB each
    bf16* Wkt = Wqt + 1024 * 1024;
    bf16* Wvt = Wkt + 1024 * 1024;
    bf16* Wot = Wvt + 1024 * 1024;
    float* Kv = (float*)(Wot + 1024 * 1024);         // 64*65*64 fp32 ~ 1.06 MB
    bf16* attn = xb;

    // x -> bf16
    cvt_bf16<<<8388608 / 256, 256, 0, stream>>>((const float4*)x, (bf16x4*)xb, 8388608);
    // weights -> transposed bf16
    dim3 tb(32, 8);
    transpose_w<<<dim3(32, 32), tb, 0, stream>>>(Wq, Wqt);
    transpose_w<<<dim3(32, 32), tb, 0, stream>>>(Wk, Wkt);
    transpose_w<<<dim3(32, 32), tb, 0, stream>>>(Wv, Wvt);
    transpose_w<<<dim3(32, 32), tb, 0, stream>>>(Wo, Wot);
    hipMemsetAsync(Kv, 0, (size_t)64 * 65 * 64 * sizeof(float), stream);

    // Qf = phi(x @ Wq)              (32768 x 1024)
    gemm_bt<2><<<dim3(8, 256), 256, 0, stream>>>(xb, 1024, Wqt, 1024, Qf, 1024, 1024);
    // Kft = phi(Wk^T x^T)           (1024 x 32768)
    gemm_bt<2><<<dim3(256, 8), 256, 0, stream>>>(Wkt, 1024, xb, 1024, Kft, 32768, 1024);
    // Vt = Wv^T x^T                 (1024 x 32768)
    gemm_bt<1><<<dim3(256, 8), 256, 0, stream>>>(Wvt, 1024, xb, 1024, Vt, 32768, 1024);
    // KvT (+K1 row) per (b,h)
    kv_reduce<<<dim3(4, 64), 256, 0, stream>>>(Kft, Vt, Kv);
    // attn = num/den                (32768 x 1024, into xb)
    attn_out<<<dim3(64, 64), 256, 0, stream>>>(Qf, Kv, attn);
    // out = attn @ Wo               (fp32)
    gemm_bt<0><<<dim3(8, 256), 256, 0, stream>>>(attn, 1024, Wot, 1024, d_out, 1024, 1024);
}

// Round 2
// 705.405 us; speedup vs baseline: 1.0501x; 1.0501x over previous
//
#include <hip/hip_runtime.h>
#include <stdint.h>
#include <stddef.h>

typedef __bf16 bf16;
typedef __attribute__((ext_vector_type(8))) __bf16 bf16x8;
typedef __attribute__((ext_vector_type(4))) __bf16 bf16x4;
typedef __attribute__((ext_vector_type(4))) float f32x4;

#define ATT_EPS 1e-6f

// async global->LDS, 16B per lane; LDS dest = wave-uniform base + lane*16
__device__ __forceinline__ void lds16(const void* g, void* l) {
    __builtin_amdgcn_global_load_lds(
        (const __attribute__((address_space(1))) void*)g,
        (__attribute__((address_space(3))) void*)l, 16, 0, 0);
}

// XCD swizzle for 2048-block grids shaped (256 "u" tiles) x (8 "v" tiles):
// blocks sharing a u-tile get flat ids spaced by 8 -> same XCD, adjacent in
// time -> the shared operand tile stays in that XCD's L2.
__device__ __forceinline__ void swizzle_uv(int lin, int& u, int& v) {
    u = (lin & 7) | ((lin >> 6) << 3); // 0..255
    v = (lin >> 3) & 7;                // 0..7
}

// ---------------------------------------------------------------------------
// fp32 -> bf16 bulk convert (x)
// ---------------------------------------------------------------------------
__global__ __launch_bounds__(256) void cvt_bf16(const float4* __restrict__ in,
                                                bf16x4* __restrict__ out, int n4) {
    int i = blockIdx.x * 256 + threadIdx.x;
    if (i < n4) {
        float4 v = in[i];
        bf16x4 o;
        o.x = (bf16)v.x; o.y = (bf16)v.y; o.z = (bf16)v.z; o.w = (bf16)v.w;
        out[i] = o;
    }
}

// ---------------------------------------------------------------------------
// W (K x N fp32, row-major) -> Wt (N x K bf16, row-major)
// ---------------------------------------------------------------------------
__global__ __launch_bounds__(256) void transpose_w(const float* __restrict__ W,
                                                   bf16* __restrict__ Wt) {
    __shared__ float tile[32][33];
    const int bx = blockIdx.x * 32, by = blockIdx.y * 32;
    const int tx = threadIdx.x, ty = threadIdx.y; // 32 x 8
#pragma unroll
    for (int j = 0; j < 32; j += 8)
        tile[ty + j][tx] = W[(size_t)(by + ty + j) * 1024 + bx + tx];
    __syncthreads();
#pragma unroll
    for (int j = 0; j < 32; j += 8)
        Wt[(size_t)(bx + ty + j) * 1024 + by + tx] = (bf16)tile[tx][ty + j];
}

// ---------------------------------------------------------------------------
// C[m][n] = sum_k A[m][k] * Bt[n][k]   (both operands k-contiguous, bf16)
// M = 32768 (u, 256 tiles), N = 1024 (v, 8 tiles), 1D grid of 2048, swizzled.
// MODE: 0 = store fp32, 2 = phi(x)=elu(x)+1 then bf16
// ---------------------------------------------------------------------------
template <int MODE>
__global__ __launch_bounds__(256) void gemm_bt(const bf16* __restrict__ A, int lda,
                                               const bf16* __restrict__ B, int ldb,
                                               void* __restrict__ C, int ldc, int K) {
    __shared__ bf16 sA[128 * 32] __attribute__((aligned(16)));
    __shared__ bf16 sB[128 * 32] __attribute__((aligned(16)));
    const int t = threadIdx.x;
    const int wave = t >> 6;
    const int lane = t & 63;
    int u, v;
    swizzle_uv(blockIdx.x, u, v);
    const int tileM = u * 128;
    const int tileN = v * 128;
    const int wm = (wave >> 1) * 64;
    const int wn = (wave & 1) * 64;

    f32x4 acc[4][4] = {};

    const int srow = t >> 2;          // 0..63
    const int scol = (t & 3) * 8;     // k offset within BK
    const bf16* a0 = A + (size_t)(tileM + srow) * lda + scol;
    const bf16* a1 = A + (size_t)(tileM + 64 + srow) * lda + scol;
    const bf16* b0 = B + (size_t)(tileN + srow) * ldb + scol;
    const bf16* b1 = B + (size_t)(tileN + 64 + srow) * ldb + scol;
    bf16* dA0 = sA + wave * 512;
    bf16* dA1 = sA + 2048 + wave * 512;
    bf16* dB0 = sB + wave * 512;
    bf16* dB1 = sB + 2048 + wave * 512;

    const int rm = lane & 15;
    const int qk = (lane >> 4) * 8;

    for (int k0 = 0; k0 < K; k0 += 32) {
        lds16(a0 + k0, dA0);
        lds16(a1 + k0, dA1);
        lds16(b0 + k0, dB0);
        lds16(b1 + k0, dB1);
        __builtin_amdgcn_s_waitcnt(0);
        __syncthreads();
        bf16x8 af[4], bfr[4];
#pragma unroll
        for (int mi = 0; mi < 4; mi++)
            af[mi] = *(const bf16x8*)&sA[(wm + mi * 16 + rm) * 32 + qk];
#pragma unroll
        for (int ni = 0; ni < 4; ni++)
            bfr[ni] = *(const bf16x8*)&sB[(wn + ni * 16 + rm) * 32 + qk];
#pragma unroll
        for (int mi = 0; mi < 4; mi++)
#pragma unroll
            for (int ni = 0; ni < 4; ni++)
                acc[mi][ni] = __builtin_amdgcn_mfma_f32_16x16x32_bf16(
                    af[mi], bfr[ni], acc[mi][ni], 0, 0, 0);
        __syncthreads();
    }

    const int row0 = (lane >> 4) * 4;
    const int col = lane & 15;
#pragma unroll
    for (int mi = 0; mi < 4; mi++) {
#pragma unroll
        for (int ni = 0; ni < 4; ni++) {
#pragma unroll
            for (int r = 0; r < 4; r++) {
                int gm = tileM + wm + mi * 16 + row0 + r;
                int gn = tileN + wn + ni * 16 + col;
                float val = acc[mi][ni][r];
                if (MODE == 2) val = (val > 0.f) ? (val + 1.f) : __expf(val);
                if (MODE == 0)
                    ((float*)C)[(size_t)gm * ldc + gn] = val;
                else
                    ((bf16*)C)[(size_t)gm * ldc + gn] = (bf16)val;
            }
        }
    }
}

// ---------------------------------------------------------------------------
// Fused K+V transposed projection:
//   Kft[d][l] = phi(sum_k Wkt[d][k] * xb[l][k]),  Vt[d][l] = sum_k Wvt[d][k]*xb[l][k]
// u (256 tiles) = l dimension (shared xb tile), v (8 tiles) = d dimension.
// Stages xb once per k-step, 32 MFMAs per k-step (2x density of split kernels).
// ---------------------------------------------------------------------------
__global__ __launch_bounds__(256, 2) void kv_proj(const bf16* __restrict__ Wkt,
                                                  const bf16* __restrict__ Wvt,
                                                  const bf16* __restrict__ xb,
                                                  bf16* __restrict__ Kft,
                                                  bf16* __restrict__ Vt) {
    __shared__ bf16 sK[128 * 32] __attribute__((aligned(16)));
    __shared__ bf16 sV[128 * 32] __attribute__((aligned(16)));
    __shared__ bf16 sX[128 * 32] __attribute__((aligned(16)));
    const int t = threadIdx.x;
    const int wave = t >> 6;
    const int lane = t & 63;
    int u, v;
    swizzle_uv(blockIdx.x, u, v);
    const int tileM = v * 128; // d
    const int tileN = u * 128; // l
    const int wm = (wave >> 1) * 64;
    const int wn = (wave & 1) * 64;

    f32x4 accK[4][4] = {};
    f32x4 accV[4][4] = {};

    const int srow = t >> 2;
    const int scol = (t & 3) * 8;
    const bf16* k0p = Wkt + (size_t)(tileM + srow) * 1024 + scol;
    const bf16* k1p = k0p + (size_t)64 * 1024;
    const bf16* v0p = Wvt + (size_t)(tileM + srow) * 1024 + scol;
    const bf16* v1p = v0p + (size_t)64 * 1024;
    const bf16* x0p = xb + (size_t)(tileN + srow) * 1024 + scol;
    const bf16* x1p = x0p + (size_t)64 * 1024;
    bf16* dK0 = sK + wave * 512;
    bf16* dK1 = sK + 2048 + wave * 512;
    bf16* dV0 = sV + wave * 512;
    bf16* dV1 = sV + 2048 + wave * 512;
    bf16* dX0 = sX + wave * 512;
    bf16* dX1 = sX + 2048 + wave * 512;

    const int rm = lane & 15;
    const int qk = (lane >> 4) * 8;

    for (int k0 = 0; k0 < 1024; k0 += 32) {
        lds16(k0p + k0, dK0);
        lds16(k1p + k0, dK1);
        lds16(v0p + k0, dV0);
        lds16(v1p + k0, dV1);
        lds16(x0p + k0, dX0);
        lds16(x1p + k0, dX1);
        __builtin_amdgcn_s_waitcnt(0);
        __syncthreads();
        bf16x8 bfr[4], afK[4], afV[4];
#pragma unroll
        for (int ni = 0; ni < 4; ni++)
            bfr[ni] = *(const bf16x8*)&sX[(wn + ni * 16 + rm) * 32 + qk];
#pragma unroll
        for (int mi = 0; mi < 4; mi++) {
            afK[mi] = *(const bf16x8*)&sK[(wm + mi * 16 + rm) * 32 + qk];
            afV[mi] = *(const bf16x8*)&sV[(wm + mi * 16 + rm) * 32 + qk];
        }
#pragma unroll
        for (int mi = 0; mi < 4; mi++)
#pragma unroll
            for (int ni = 0; ni < 4; ni++) {
                accK[mi][ni] = __builtin_amdgcn_mfma_f32_16x16x32_bf16(
                    afK[mi], bfr[ni], accK[mi][ni], 0, 0, 0);
                accV[mi][ni] = __builtin_amdgcn_mfma_f32_16x16x32_bf16(
                    afV[mi], bfr[ni], accV[mi][ni], 0, 0, 0);
            }
        __syncthreads();
    }

    const int row0 = (lane >> 4) * 4;
    const int col = lane & 15;
#pragma unroll
    for (int mi = 0; mi < 4; mi++) {
#pragma unroll
        for (int ni = 0; ni < 4; ni++) {
#pragma unroll
            for (int r = 0; r < 4; r++) {
                int gm = tileM + wm + mi * 16 + row0 + r;      // d
                int gn = tileN + wn + ni * 16 + col;           // l
                float kv_ = accK[mi][ni][r];
                kv_ = (kv_ > 0.f) ? (kv_ + 1.f) : __expf(kv_);
                Kft[(size_t)gm * 32768 + gn] = (bf16)kv_;
                Vt[(size_t)gm * 32768 + gn] = (bf16)accV[mi][ni][r];
            }
        }
    }
}

// ---------------------------------------------------------------------------
// Phase 2: per (b,h):  KvT[n][m] += sum_l Kf[l][m] V[l][n];  KvT[64][m] = K1[m]
// ---------------------------------------------------------------------------
__global__ __launch_bounds__(256) void kv_reduce(const bf16* __restrict__ Kft,
                                                 const bf16* __restrict__ Vt,
                                                 float* __restrict__ Kv) {
    const int chunk = blockIdx.x; // 0..3
    const int bh = blockIdx.y;    // 0..63
    const int b = bh >> 4, h = bh & 15;
    __shared__ bf16 sA[64 * 32] __attribute__((aligned(16)));
    __shared__ bf16 sB[64 * 32] __attribute__((aligned(16)));
    const int t = threadIdx.x, wave = t >> 6, lane = t & 63;
    const size_t cbase = (size_t)b * 8192 + (size_t)chunk * 2048;
    const int srow = t >> 2, scol = (t & 3) * 8;
    const bf16* a0 = Kft + (size_t)(h * 64 + srow) * 32768 + cbase + scol;
    const bf16* b0 = Vt + (size_t)(h * 64 + srow) * 32768 + cbase + scol;
    bf16* dA = sA + wave * 512;
    bf16* dB = sB + wave * 512;
    const int rm = lane & 15, qk = (lane >> 4) * 8;

    f32x4 acc[4] = {};
    f32x4 acc1 = {0.f, 0.f, 0.f, 0.f};
    bf16x8 ones;
#pragma unroll
    for (int j = 0; j < 8; j++) ones[j] = (bf16)1.0f;

    for (int k0 = 0; k0 < 2048; k0 += 32) {
        lds16(a0 + k0, dA);
        lds16(b0 + k0, dB);
        __builtin_amdgcn_s_waitcnt(0);
        __syncthreads();
        bf16x8 af = *(const bf16x8*)&sA[(wave * 16 + rm) * 32 + qk];
        bf16x8 bfr[4];
#pragma unroll
        for (int ni = 0; ni < 4; ni++)
            bfr[ni] = *(const bf16x8*)&sB[(ni * 16 + rm) * 32 + qk];
#pragma unroll
        for (int ni = 0; ni < 4; ni++)
            acc[ni] = __builtin_amdgcn_mfma_f32_16x16x32_bf16(af, bfr[ni], acc[ni], 0, 0, 0);
        acc1 = __builtin_amdgcn_mfma_f32_16x16x32_bf16(af, ones, acc1, 0, 0, 0);
        __syncthreads();
    }

    float* out = Kv + bh * 65 * 64;
    const int row0 = (lane >> 4) * 4, col = lane & 15;
    const int m0 = wave * 16 + row0;
#pragma unroll
    for (int ni = 0; ni < 4; ni++)
#pragma unroll
        for (int r = 0; r < 4; r++)
            atomicAdd(&out[(ni * 16 + col) * 64 + m0 + r], acc[ni][r]);
    if (col == 0) {
#pragma unroll
        for (int r = 0; r < 4; r++) atomicAdd(&out[64 * 64 + m0 + r], acc1[r]);
    }
}

// ---------------------------------------------------------------------------
// Phase 3: attn[l][h*64+n] = (sum_m Qf[l][m] KvT[n][m]) / (dot(Qf, K1) + eps)
// ---------------------------------------------------------------------------
__global__ __launch_bounds__(256) void attn_out(const bf16* __restrict__ Qf,
                                                const float* __restrict__ Kv,
                                                bf16* __restrict__ attn) {
    const int lt = blockIdx.x; // 0..63
    const int bh = blockIdx.y; // 0..63
    const int b = bh >> 4, h = bh & 15;
    __shared__ bf16 sQ[128 * 64] __attribute__((aligned(16)));
    __shared__ bf16 sB[80 * 64] __attribute__((aligned(16)));
    __shared__ float den[128];
    const int t = threadIdx.x, wave = t >> 6, lane = t & 63;
    const int qrow = t >> 3, qc = (t & 7) * 8;
    const bf16* qp = Qf + (size_t)(b * 8192 + lt * 128 + qrow) * 1024 + h * 64 + qc;
#pragma unroll
    for (int i = 0; i < 4; i++)
        lds16(qp + (size_t)i * 32 * 1024, sQ + i * 2048 + wave * 512);
    const float* kv = Kv + bh * 65 * 64;
    for (int idx = t; idx < 80 * 64; idx += 256) {
        int n = idx >> 6, k2 = idx & 63;
        sB[idx] = (n < 65) ? (bf16)kv[n * 64 + k2] : (bf16)0.f;
    }
    __builtin_amdgcn_s_waitcnt(0);
    __syncthreads();

    f32x4 acc[2][5] = {};
    const int rm = lane & 15, qk = (lane >> 4) * 8;
#pragma unroll
    for (int k0 = 0; k0 < 64; k0 += 32) {
        bf16x8 af[2], bfr[5];
#pragma unroll
        for (int mi = 0; mi < 2; mi++)
            af[mi] = *(const bf16x8*)&sQ[(wave * 32 + mi * 16 + rm) * 64 + k0 + qk];
#pragma unroll
        for (int ni = 0; ni < 5; ni++)
            bfr[ni] = *(const bf16x8*)&sB[(ni * 16 + rm) * 64 + k0 + qk];
#pragma unroll
        for (int mi = 0; mi < 2; mi++)
#pragma unroll
            for (int ni = 0; ni < 5; ni++)
                acc[mi][ni] = __builtin_amdgcn_mfma_f32_16x16x32_bf16(
                    af[mi], bfr[ni], acc[mi][ni], 0, 0, 0);
    }

    const int row0 = (lane >> 4) * 4, col = lane & 15;
    if (col == 0) {
#pragma unroll
        for (int mi = 0; mi < 2; mi++)
#pragma unroll
            for (int r = 0; r < 4; r++)
                den[wave * 32 + mi * 16 + row0 + r] = acc[mi][4][r] + ATT_EPS;
    }
    __syncthreads();
#pragma unroll
    for (int mi = 0; mi < 2; mi++) {
#pragma unroll
        for (int ni = 0; ni < 4; ni++) {
#pragma unroll
            for (int r = 0; r < 4; r++) {
                int rl = wave * 32 + mi * 16 + row0 + r;
                float vv = acc[mi][ni][r] / den[rl];
                attn[(size_t)(b * 8192 + lt * 128 + rl) * 1024 + h * 64 + ni * 16 + col] =
                    (bf16)vv;
            }
        }
    }
}

// ---------------------------------------------------------------------------
extern "C" void kernel_launch(void* const* d_in, const int* in_sizes, int n_in,
                              void* d_out, int out_size, void* d_ws, size_t ws_size,
                              hipStream_t stream) {
    const float* x  = (const float*)d_in[0];
    const float* Wq = (const float*)d_in[1];
    const float* Wk = (const float*)d_in[2];
    const float* Wv = (const float*)d_in[3];
    const float* Wo = (const float*)d_in[4];

    char* ws = (char*)d_ws;
    bf16* xb  = (bf16*)ws;                           // 64 MB, reused as attn
    bf16* Qf  = (bf16*)(ws + ((size_t)64 << 20));    // 64 MB
    bf16* Kft = (bf16*)(ws + ((size_t)128 << 20));   // 64 MB
    bf16* Vt  = (bf16*)(ws + ((size_t)192 << 20));   // 64 MB
    bf16* Wqt = (bf16*)(ws + ((size_t)256 << 20));   // 2 MB each
    bf16* Wkt = Wqt + 1024 * 1024;
    bf16* Wvt = Wkt + 1024 * 1024;
    bf16* Wot = Wvt + 1024 * 1024;
    float* Kv = (float*)(Wot + 1024 * 1024);         // 64*65*64 fp32 ~ 1.06 MB
    bf16* attn = xb;

    // x -> bf16
    cvt_bf16<<<8388608 / 256, 256, 0, stream>>>((const float4*)x, (bf16x4*)xb, 8388608);
    // weights -> transposed bf16
    dim3 tb(32, 8);
    transpose_w<<<dim3(32, 32), tb, 0, stream>>>(Wq, Wqt);
    transpose_w<<<dim3(32, 32), tb, 0, stream>>>(Wk, Wkt);
    transpose_w<<<dim3(32, 32), tb, 0, stream>>>(Wv, Wvt);
    transpose_w<<<dim3(32, 32), tb, 0, stream>>>(Wo, Wot);
    hipMemsetAsync(Kv, 0, (size_t)64 * 65 * 64 * sizeof(float), stream);

    // Qf = phi(x @ Wq)              (32768 x 1024)
    gemm_bt<2><<<2048, 256, 0, stream>>>(xb, 1024, Wqt, 1024, Qf, 1024, 1024);
    // Kft = phi(Wk^T x^T), Vt = Wv^T x^T   (1024 x 32768, fused)
    kv_proj<<<2048, 256, 0, stream>>>(Wkt, Wvt, xb, Kft, Vt);
    // KvT (+K1 row) per (b,h)
    kv_reduce<<<dim3(4, 64), 256, 0, stream>>>(Kft, Vt, Kv);
    // attn = num/den                (32768 x 1024, into xb)
    attn_out<<<dim3(64, 64), 256, 0, stream>>>(Qf, Kv, attn);
    // out = attn @ Wo               (fp32)
    gemm_bt<0><<<2048, 256, 0, stream>>>(attn, 1024, Wot, 1024, d_out, 1024, 1024);
}

// Round 3
// 681.199 us; speedup vs baseline: 1.0874x; 1.0355x over previous
//
#include <hip/hip_runtime.h>
#include <stdint.h>
#include <stddef.h>

typedef __bf16 bf16;
typedef __attribute__((ext_vector_type(8))) __bf16 bf16x8;
typedef __attribute__((ext_vector_type(4))) __bf16 bf16x4;
typedef __attribute__((ext_vector_type(4))) float f32x4;

#define ATT_EPS 1e-6f

// async global->LDS, 16B per lane; LDS dest = wave-uniform base + lane*16
__device__ __forceinline__ void lds16(const void* g, void* l) {
    __builtin_amdgcn_global_load_lds(
        (const __attribute__((address_space(1))) void*)g,
        (__attribute__((address_space(3))) void*)l, 16, 0, 0);
}

// XCD swizzle for 2048-block grids shaped (256 "u" tiles) x (8 "v" tiles)
__device__ __forceinline__ void swizzle_uv(int lin, int& u, int& v) {
    u = (lin & 7) | ((lin >> 6) << 3);
    v = (lin >> 3) & 7;
}

// ---------------------------------------------------------------------------
__global__ __launch_bounds__(256) void cvt_bf16(const float4* __restrict__ in,
                                                bf16x4* __restrict__ out, int n4) {
    int i = blockIdx.x * 256 + threadIdx.x;
    if (i < n4) {
        float4 v = in[i];
        bf16x4 o;
        o.x = (bf16)v.x; o.y = (bf16)v.y; o.z = (bf16)v.z; o.w = (bf16)v.w;
        out[i] = o;
    }
}

// ---------------------------------------------------------------------------
__global__ __launch_bounds__(256) void transpose_w(const float* __restrict__ W,
                                                   bf16* __restrict__ Wt) {
    __shared__ float tile[32][33];
    const int bx = blockIdx.x * 32, by = blockIdx.y * 32;
    const int tx = threadIdx.x, ty = threadIdx.y; // 32 x 8
#pragma unroll
    for (int j = 0; j < 32; j += 8)
        tile[ty + j][tx] = W[(size_t)(by + ty + j) * 1024 + bx + tx];
    __syncthreads();
#pragma unroll
    for (int j = 0; j < 32; j += 8)
        Wt[(size_t)(bx + ty + j) * 1024 + by + tx] = (bf16)tile[tx][ty + j];
}

// ---------------------------------------------------------------------------
// C[m][n] = sum_k A[m][k] * Bt[n][k]; 128x128 tile, BK=32, m97 recipe.
// MODE: 0 = store fp32 direct (64B segments, no RMW), 2 = phi + bf16 via LDS repack
// ---------------------------------------------------------------------------
template <int MODE>
__global__ __launch_bounds__(256) void gemm_bt(const bf16* __restrict__ A, int lda,
                                               const bf16* __restrict__ B, int ldb,
                                               void* __restrict__ C, int ldc, int K) {
    constexpr int EP_STRIDE = 136; // padded bf16 stride: 272B rows, 16B-aligned
    constexpr int SMEM_ELEMS = (MODE == 2) ? 128 * EP_STRIDE : 8192;
    __shared__ bf16 smem[SMEM_ELEMS] __attribute__((aligned(16)));
    bf16* sA = smem;
    bf16* sB = smem + 4096;
    const int t = threadIdx.x;
    const int wave = t >> 6;
    const int lane = t & 63;
    int u, v;
    swizzle_uv(blockIdx.x, u, v);
    const int tileM = u * 128;
    const int tileN = v * 128;
    const int wm = (wave >> 1) * 64;
    const int wn = (wave & 1) * 64;

    f32x4 acc[4][4] = {};

    const int srow = t >> 2;
    const int scol = (t & 3) * 8;
    const bf16* a0 = A + (size_t)(tileM + srow) * lda + scol;
    const bf16* a1 = A + (size_t)(tileM + 64 + srow) * lda + scol;
    const bf16* b0 = B + (size_t)(tileN + srow) * ldb + scol;
    const bf16* b1 = B + (size_t)(tileN + 64 + srow) * ldb + scol;
    bf16* dA0 = sA + wave * 512;
    bf16* dA1 = sA + 2048 + wave * 512;
    bf16* dB0 = sB + wave * 512;
    bf16* dB1 = sB + 2048 + wave * 512;

    const int rm = lane & 15;
    const int qk = (lane >> 4) * 8;

    for (int k0 = 0; k0 < K; k0 += 32) {
        lds16(a0 + k0, dA0);
        lds16(a1 + k0, dA1);
        lds16(b0 + k0, dB0);
        lds16(b1 + k0, dB1);
        __builtin_amdgcn_s_waitcnt(0);
        __syncthreads();
        bf16x8 af[4], bfr[4];
#pragma unroll
        for (int mi = 0; mi < 4; mi++)
            af[mi] = *(const bf16x8*)&sA[(wm + mi * 16 + rm) * 32 + qk];
#pragma unroll
        for (int ni = 0; ni < 4; ni++)
            bfr[ni] = *(const bf16x8*)&sB[(wn + ni * 16 + rm) * 32 + qk];
#pragma unroll
        for (int mi = 0; mi < 4; mi++)
#pragma unroll
            for (int ni = 0; ni < 4; ni++)
                acc[mi][ni] = __builtin_amdgcn_mfma_f32_16x16x32_bf16(
                    af[mi], bfr[ni], acc[mi][ni], 0, 0, 0);
        __syncthreads();
    }

    const int row0 = (lane >> 4) * 4;
    const int col = lane & 15;
    if (MODE == 0) {
#pragma unroll
        for (int mi = 0; mi < 4; mi++)
#pragma unroll
            for (int ni = 0; ni < 4; ni++)
#pragma unroll
                for (int r = 0; r < 4; r++) {
                    int gm = tileM + wm + mi * 16 + row0 + r;
                    int gn = tileN + wn + ni * 16 + col;
                    ((float*)C)[(size_t)gm * ldc + gn] = acc[mi][ni][r];
                }
    } else {
        // scatter (phi applied) into padded LDS tile, then 256B-row vector stores
#pragma unroll
        for (int mi = 0; mi < 4; mi++)
#pragma unroll
            for (int ni = 0; ni < 4; ni++)
#pragma unroll
                for (int r = 0; r < 4; r++) {
                    float val = acc[mi][ni][r];
                    val = (val > 0.f) ? (val + 1.f) : __expf(val);
                    smem[(wm + mi * 16 + row0 + r) * EP_STRIDE + wn + ni * 16 + col] =
                        (bf16)val;
                }
        __syncthreads();
        const int er = t >> 4, ec = (t & 15) * 8;
#pragma unroll
        for (int i = 0; i < 8; i++) {
            int row = er + i * 16;
            *(bf16x8*)&((bf16*)C)[(size_t)(tileM + row) * ldc + tileN + ec] =
                *(const bf16x8*)&smem[row * EP_STRIDE + ec];
        }
    }
}

// ---------------------------------------------------------------------------
// Fused K+V transposed projection with LDS-repacked vector epilogue.
// ---------------------------------------------------------------------------
__global__ __launch_bounds__(256, 2) void kv_proj(const bf16* __restrict__ Wkt,
                                                  const bf16* __restrict__ Wvt,
                                                  const bf16* __restrict__ xb,
                                                  bf16* __restrict__ Kft,
                                                  bf16* __restrict__ Vt) {
    constexpr int EP_STRIDE = 136;
    __shared__ bf16 smem[128 * EP_STRIDE] __attribute__((aligned(16))); // 34 KB union
    bf16* sK = smem;
    bf16* sV = smem + 4096;
    bf16* sX = smem + 8192;
    const int t = threadIdx.x;
    const int wave = t >> 6;
    const int lane = t & 63;
    int u, v;
    swizzle_uv(blockIdx.x, u, v);
    const int tileM = v * 128; // d
    const int tileN = u * 128; // l
    const int wm = (wave >> 1) * 64;
    const int wn = (wave & 1) * 64;

    f32x4 accK[4][4] = {};
    f32x4 accV[4][4] = {};

    const int srow = t >> 2;
    const int scol = (t & 3) * 8;
    const bf16* k0p = Wkt + (size_t)(tileM + srow) * 1024 + scol;
    const bf16* k1p = k0p + (size_t)64 * 1024;
    const bf16* v0p = Wvt + (size_t)(tileM + srow) * 1024 + scol;
    const bf16* v1p = v0p + (size_t)64 * 1024;
    const bf16* x0p = xb + (size_t)(tileN + srow) * 1024 + scol;
    const bf16* x1p = x0p + (size_t)64 * 1024;
    bf16* dK0 = sK + wave * 512;
    bf16* dK1 = sK + 2048 + wave * 512;
    bf16* dV0 = sV + wave * 512;
    bf16* dV1 = sV + 2048 + wave * 512;
    bf16* dX0 = sX + wave * 512;
    bf16* dX1 = sX + 2048 + wave * 512;

    const int rm = lane & 15;
    const int qk = (lane >> 4) * 8;

    for (int k0 = 0; k0 < 1024; k0 += 32) {
        lds16(k0p + k0, dK0);
        lds16(k1p + k0, dK1);
        lds16(v0p + k0, dV0);
        lds16(v1p + k0, dV1);
        lds16(x0p + k0, dX0);
        lds16(x1p + k0, dX1);
        __builtin_amdgcn_s_waitcnt(0);
        __syncthreads();
        bf16x8 bfr[4], afK[4], afV[4];
#pragma unroll
        for (int ni = 0; ni < 4; ni++)
            bfr[ni] = *(const bf16x8*)&sX[(wn + ni * 16 + rm) * 32 + qk];
#pragma unroll
        for (int mi = 0; mi < 4; mi++) {
            afK[mi] = *(const bf16x8*)&sK[(wm + mi * 16 + rm) * 32 + qk];
            afV[mi] = *(const bf16x8*)&sV[(wm + mi * 16 + rm) * 32 + qk];
        }
#pragma unroll
        for (int mi = 0; mi < 4; mi++)
#pragma unroll
            for (int ni = 0; ni < 4; ni++) {
                accK[mi][ni] = __builtin_amdgcn_mfma_f32_16x16x32_bf16(
                    afK[mi], bfr[ni], accK[mi][ni], 0, 0, 0);
                accV[mi][ni] = __builtin_amdgcn_mfma_f32_16x16x32_bf16(
                    afV[mi], bfr[ni], accV[mi][ni], 0, 0, 0);
            }
        __syncthreads();
    }

    const int row0 = (lane >> 4) * 4;
    const int col = lane & 15;
    const int er = t >> 4, ec = (t & 15) * 8;

    // --- K tile (phi) ---
#pragma unroll
    for (int mi = 0; mi < 4; mi++)
#pragma unroll
        for (int ni = 0; ni < 4; ni++)
#pragma unroll
            for (int r = 0; r < 4; r++) {
                float val = accK[mi][ni][r];
                val = (val > 0.f) ? (val + 1.f) : __expf(val);
                smem[(wm + mi * 16 + row0 + r) * EP_STRIDE + wn + ni * 16 + col] =
                    (bf16)val;
            }
    __syncthreads();
#pragma unroll
    for (int i = 0; i < 8; i++) {
        int row = er + i * 16;
        *(bf16x8*)&Kft[(size_t)(tileM + row) * 32768 + tileN + ec] =
            *(const bf16x8*)&smem[row * EP_STRIDE + ec];
    }
    __syncthreads();
    // --- V tile ---
#pragma unroll
    for (int mi = 0; mi < 4; mi++)
#pragma unroll
        for (int ni = 0; ni < 4; ni++)
#pragma unroll
            for (int r = 0; r < 4; r++)
                smem[(wm + mi * 16 + row0 + r) * EP_STRIDE + wn + ni * 16 + col] =
                    (bf16)accV[mi][ni][r];
    __syncthreads();
#pragma unroll
    for (int i = 0; i < 8; i++) {
        int row = er + i * 16;
        *(bf16x8*)&Vt[(size_t)(tileM + row) * 32768 + tileN + ec] =
            *(const bf16x8*)&smem[row * EP_STRIDE + ec];
    }
}

// ---------------------------------------------------------------------------
// Phase 2: per (b,h): KvT[n][m] += sum_l Kf[l][m] V[l][n];  row 64 = K1
// ---------------------------------------------------------------------------
__global__ __launch_bounds__(256) void kv_reduce(const bf16* __restrict__ Kft,
                                                 const bf16* __restrict__ Vt,
                                                 float* __restrict__ Kv) {
    const int chunk = blockIdx.x; // 0..7
    const int bh = blockIdx.y;    // 0..63
    const int b = bh >> 4, h = bh & 15;
    __shared__ bf16 sA[64 * 32] __attribute__((aligned(16)));
    __shared__ bf16 sB[64 * 32] __attribute__((aligned(16)));
    const int t = threadIdx.x, wave = t >> 6, lane = t & 63;
    const size_t cbase = (size_t)b * 8192 + (size_t)chunk * 1024;
    const int srow = t >> 2, scol = (t & 3) * 8;
    const bf16* a0 = Kft + (size_t)(h * 64 + srow) * 32768 + cbase + scol;
    const bf16* b0 = Vt + (size_t)(h * 64 + srow) * 32768 + cbase + scol;
    bf16* dA = sA + wave * 512;
    bf16* dB = sB + wave * 512;
    const int rm = lane & 15, qk = (lane >> 4) * 8;

    f32x4 acc[4] = {};
    f32x4 acc1 = {0.f, 0.f, 0.f, 0.f};
    bf16x8 ones;
#pragma unroll
    for (int j = 0; j < 8; j++) ones[j] = (bf16)1.0f;

    for (int k0 = 0; k0 < 1024; k0 += 32) {
        lds16(a0 + k0, dA);
        lds16(b0 + k0, dB);
        __builtin_amdgcn_s_waitcnt(0);
        __syncthreads();
        bf16x8 af = *(const bf16x8*)&sA[(wave * 16 + rm) * 32 + qk];
        bf16x8 bfr[4];
#pragma unroll
        for (int ni = 0; ni < 4; ni++)
            bfr[ni] = *(const bf16x8*)&sB[(ni * 16 + rm) * 32 + qk];
#pragma unroll
        for (int ni = 0; ni < 4; ni++)
            acc[ni] = __builtin_amdgcn_mfma_f32_16x16x32_bf16(af, bfr[ni], acc[ni], 0, 0, 0);
        acc1 = __builtin_amdgcn_mfma_f32_16x16x32_bf16(af, ones, acc1, 0, 0, 0);
        __syncthreads();
    }

    float* out = Kv + bh * 65 * 64;
    const int row0 = (lane >> 4) * 4, col = lane & 15;
    const int m0 = wave * 16 + row0;
#pragma unroll
    for (int ni = 0; ni < 4; ni++)
#pragma unroll
        for (int r = 0; r < 4; r++)
            atomicAdd(&out[(ni * 16 + col) * 64 + m0 + r], acc[ni][r]);
    if (col == 0) {
#pragma unroll
        for (int r = 0; r < 4; r++) atomicAdd(&out[64 * 64 + m0 + r], acc1[r]);
    }
}

// ---------------------------------------------------------------------------
// Phase 3: attn = num/den, LDS-repacked vector epilogue.
// ---------------------------------------------------------------------------
__global__ __launch_bounds__(256) void attn_out(const bf16* __restrict__ Qf,
                                                const float* __restrict__ Kv,
                                                bf16* __restrict__ attn) {
    const int lt = blockIdx.x; // 0..63
    const int bh = blockIdx.y; // 0..63
    const int b = bh >> 4, h = bh & 15;
    constexpr int EP_STRIDE = 80;
    // union: staging sQ (8192) + sB (5120) vs epilogue 128*80 = 10240
    __shared__ bf16 smem[13312] __attribute__((aligned(16)));
    __shared__ float den[128];
    bf16* sQ = smem;
    bf16* sB = smem + 8192;
    const int t = threadIdx.x, wave = t >> 6, lane = t & 63;
    const int qrow = t >> 3, qc = (t & 7) * 8;
    const bf16* qp = Qf + (size_t)(b * 8192 + lt * 128 + qrow) * 1024 + h * 64 + qc;
#pragma unroll
    for (int i = 0; i < 4; i++)
        lds16(qp + (size_t)i * 32 * 1024, sQ + i * 2048 + wave * 512);
    const float* kv = Kv + bh * 65 * 64;
    for (int idx = t; idx < 80 * 64; idx += 256) {
        int n = idx >> 6, k2 = idx & 63;
        sB[idx] = (n < 65) ? (bf16)kv[n * 64 + k2] : (bf16)0.f;
    }
    __builtin_amdgcn_s_waitcnt(0);
    __syncthreads();

    f32x4 acc[2][5] = {};
    const int rm = lane & 15, qk = (lane >> 4) * 8;
#pragma unroll
    for (int k0 = 0; k0 < 64; k0 += 32) {
        bf16x8 af[2], bfr[5];
#pragma unroll
        for (int mi = 0; mi < 2; mi++)
            af[mi] = *(const bf16x8*)&sQ[(wave * 32 + mi * 16 + rm) * 64 + k0 + qk];
#pragma unroll
        for (int ni = 0; ni < 5; ni++)
            bfr[ni] = *(const bf16x8*)&sB[(ni * 16 + rm) * 64 + k0 + qk];
#pragma unroll
        for (int mi = 0; mi < 2; mi++)
#pragma unroll
            for (int ni = 0; ni < 5; ni++)
                acc[mi][ni] = __builtin_amdgcn_mfma_f32_16x16x32_bf16(
                    af[mi], bfr[ni], acc[mi][ni], 0, 0, 0);
    }

    const int row0 = (lane >> 4) * 4, col = lane & 15;
    if (col == 0) {
#pragma unroll
        for (int mi = 0; mi < 2; mi++)
#pragma unroll
            for (int r = 0; r < 4; r++)
                den[wave * 32 + mi * 16 + row0 + r] = acc[mi][4][r] + ATT_EPS;
    }
    __syncthreads();
    // scatter num/den into padded LDS, then 128B-row vector stores
#pragma unroll
    for (int mi = 0; mi < 2; mi++)
#pragma unroll
        for (int ni = 0; ni < 4; ni++)
#pragma unroll
            for (int r = 0; r < 4; r++) {
                int rl = wave * 32 + mi * 16 + row0 + r;
                smem[rl * EP_STRIDE + ni * 16 + col] =
                    (bf16)(acc[mi][ni][r] / den[rl]);
            }
    __syncthreads();
    const int er = t >> 3, ec = (t & 7) * 8;
#pragma unroll
    for (int i = 0; i < 4; i++) {
        int row = er + i * 32;
        *(bf16x8*)&attn[(size_t)(b * 8192 + lt * 128 + row) * 1024 + h * 64 + ec] =
            *(const bf16x8*)&smem[row * EP_STRIDE + ec];
    }
}

// ---------------------------------------------------------------------------
extern "C" void kernel_launch(void* const* d_in, const int* in_sizes, int n_in,
                              void* d_out, int out_size, void* d_ws, size_t ws_size,
                              hipStream_t stream) {
    const float* x  = (const float*)d_in[0];
    const float* Wq = (const float*)d_in[1];
    const float* Wk = (const float*)d_in[2];
    const float* Wv = (const float*)d_in[3];
    const float* Wo = (const float*)d_in[4];

    char* ws = (char*)d_ws;
    bf16* xb  = (bf16*)ws;                           // 64 MB, reused as attn
    bf16* Qf  = (bf16*)(ws + ((size_t)64 << 20));    // 64 MB
    bf16* Kft = (bf16*)(ws + ((size_t)128 << 20));   // 64 MB
    bf16* Vt  = (bf16*)(ws + ((size_t)192 << 20));   // 64 MB
    bf16* Wqt = (bf16*)(ws + ((size_t)256 << 20));   // 2 MB each
    bf16* Wkt = Wqt + 1024 * 1024;
    bf16* Wvt = Wkt + 1024 * 1024;
    bf16* Wot = Wvt + 1024 * 1024;
    float* Kv = (float*)(Wot + 1024 * 1024);         // 64*65*64 fp32
    bf16* attn = xb;

    cvt_bf16<<<8388608 / 256, 256, 0, stream>>>((const float4*)x, (bf16x4*)xb, 8388608);
    dim3 tb(32, 8);
    transpose_w<<<dim3(32, 32), tb, 0, stream>>>(Wq, Wqt);
    transpose_w<<<dim3(32, 32), tb, 0, stream>>>(Wk, Wkt);
    transpose_w<<<dim3(32, 32), tb, 0, stream>>>(Wv, Wvt);
    transpose_w<<<dim3(32, 32), tb, 0, stream>>>(Wo, Wot);
    hipMemsetAsync(Kv, 0, (size_t)64 * 65 * 64 * sizeof(float), stream);

    // Qf = phi(x @ Wq)
    gemm_bt<2><<<2048, 256, 0, stream>>>(xb, 1024, Wqt, 1024, Qf, 1024, 1024);
    // Kft = phi(Wk^T x^T), Vt = Wv^T x^T (fused)
    kv_proj<<<2048, 256, 0, stream>>>(Wkt, Wvt, xb, Kft, Vt);
    // KvT (+K1 row) per (b,h), 8 l-chunks
    kv_reduce<<<dim3(8, 64), 256, 0, stream>>>(Kft, Vt, Kv);
    // attn = num/den (into xb)
    attn_out<<<dim3(64, 64), 256, 0, stream>>>(Qf, Kv, attn);
    // out = attn @ Wo (fp32)
    gemm_bt<0><<<2048, 256, 0, stream>>>(attn, 1024, Wot, 1024, d_out, 1024, 1024);
}